// Round 2
// baseline (290.251 us; speedup 1.0000x reference)
//
#include <hip/hip_runtime.h>

typedef unsigned short ushort;
typedef __attribute__((ext_vector_type(4))) float  f32x4;
typedef __attribute__((ext_vector_type(8))) short  s16x8;
typedef __attribute__((ext_vector_type(4))) ushort u16x4;

#define MFMA16(a, b, c) __builtin_amdgcn_mfma_f32_16x16x32_bf16((a), (b), (c), 0, 0, 0)

__device__ __forceinline__ ushort f2bf(float f) {
    unsigned u = __builtin_bit_cast(unsigned, f);
    u = (u + 0x7FFF + ((u >> 16) & 1)) >> 16;   // RNE
    return (ushort)u;
}

__device__ __forceinline__ void gload_lds16(const ushort* g, ushort* l) {
    __builtin_amdgcn_global_load_lds(
        (const __attribute__((address_space(1))) void*)g,
        (__attribute__((address_space(3))) void*)l, 16, 0, 0);
}

// ---------------------------------------------------------------------------
// fp32 -> bf16 conversion (grid-stride, float4 in / 8B out)
// ---------------------------------------------------------------------------
__global__ __launch_bounds__(256) void cvt_f32_bf16(
    const float* __restrict__ in, ushort* __restrict__ out, int n4)
{
    int i = blockIdx.x * blockDim.x + threadIdx.x;
    const int stride = gridDim.x * blockDim.x;
    for (; i < n4; i += stride) {
        const float4 v = ((const float4*)in)[i];
        u16x4 o;
        o[0] = f2bf(v.x); o[1] = f2bf(v.y); o[2] = f2bf(v.z); o[3] = f2bf(v.w);
        ((u16x4*)out)[i] = o;
    }
}

// ---------------------------------------------------------------------------
// 128x128 tile GEMM mainloop (m97 structure): C[row0..+128][col0..+128] +=
// A[M][K] * B[N][K]^T, both row-major k-contiguous bf16. 256 thr = 4 waves 2x2.
// Each wave computes a 64x64 sub-tile as acc[4][4] of 16x16 fragments.
// ---------------------------------------------------------------------------
__device__ __forceinline__ void gemm128_mainloop(
    const ushort* __restrict__ A, const ushort* __restrict__ B, int K,
    int row0, int col0, ushort* As, ushort* Bs, f32x4 acc[4][4])
{
    const int t  = threadIdx.x;
    const int l  = t & 63;
    const int w  = t >> 6;
    const int lr = l & 15, lg = l >> 4;
    const int wm = w >> 1, wn = w & 1;

#pragma unroll
    for (int m = 0; m < 4; m++)
#pragma unroll
        for (int n = 0; n < 4; n++) acc[m][n] = (f32x4){0.f, 0.f, 0.f, 0.f};

    // staging: thread t loads 16B; linear LDS order matches global_load_lds
    // wave-uniform-base + lane*16 requirement.
    const ushort* ga0 = A + (row0 + (t >> 2)) * K + (t & 3) * 8;
    const ushort* gb0 = B + (col0 + (t >> 2)) * K + (t & 3) * 8;
    ushort* la0 = As + t * 8;
    ushort* lb0 = Bs + t * 8;
    const int rowsz = 64 * K;

    for (int k0 = 0; k0 < K; k0 += 32) {
        gload_lds16(ga0 + k0,          la0);
        gload_lds16(ga0 + rowsz + k0,  la0 + 2048);
        gload_lds16(gb0 + k0,          lb0);
        gload_lds16(gb0 + rowsz + k0,  lb0 + 2048);
        __syncthreads();

        s16x8 af[4], bfr[4];
#pragma unroll
        for (int m = 0; m < 4; m++)
            af[m] = *(const s16x8*)&As[(wm * 64 + m * 16 + lr) * 32 + lg * 8];
#pragma unroll
        for (int n = 0; n < 4; n++)
            bfr[n] = *(const s16x8*)&Bs[(wn * 64 + n * 16 + lr) * 32 + lg * 8];
#pragma unroll
        for (int m = 0; m < 4; m++)
#pragma unroll
            for (int n = 0; n < 4; n++)
                acc[m][n] = MFMA16(af[m], bfr[n], acc[m][n]);
        __syncthreads();
    }
}

// ---------------------------------------------------------------------------
// Kernel 1: QKV = x @ qkv_w^T, scatter into q[bh][n][64] (scaled), k[bh][n][64],
// vT[bh][64][n].  grid (64, 18), block 256.
// ---------------------------------------------------------------------------
__global__ __launch_bounds__(256) void qkv_gemm(
    const ushort* __restrict__ X, const ushort* __restrict__ W,
    ushort* __restrict__ qb, ushort* __restrict__ kb, ushort* __restrict__ vb)
{
    __shared__ __align__(16) ushort As[128 * 32];
    __shared__ __align__(16) ushort Bs[128 * 32];
    f32x4 acc[4][4];
    const int br = blockIdx.x, bc = blockIdx.y;
    gemm128_mainloop(X, W, 768, br * 128, bc * 128, As, Bs, acc);

    const int t = threadIdx.x, l = t & 63, w = t >> 6;
    const int lr = l & 15, lg = l >> 4, wm = w >> 1, wn = w & 1;
    const int p = (bc * 128) / 768;             // 768 % 128 == 0: p uniform per block
    const int mrow0 = br * 128 + wm * 64 + lg * 4;
    const int ecolB = bc * 128 + wn * 64 + lr;

#pragma unroll
    for (int n = 0; n < 4; n++) {
        const int e   = ecolB + n * 16;
        const int rem = e - p * 768;
        const int h   = rem >> 6;
        const int hd  = rem & 63;
#pragma unroll
        for (int m = 0; m < 4; m++) {
            const int mr = mrow0 + m * 16;      // multiple of 4; no b-crossing in 4 rows
            const int b  = mr >> 10;
            const int nn = mr & 1023;
            const f32x4 v = acc[m][n];
            const int bh = b * 12 + h;
            if (p == 0) {
                ushort* dst = qb + (bh * 1024 + nn) * 64 + hd;
#pragma unroll
                for (int r = 0; r < 4; r++) dst[r * 64] = f2bf(v[r] * 0.125f);
            } else if (p == 1) {
                ushort* dst = kb + (bh * 1024 + nn) * 64 + hd;
#pragma unroll
                for (int r = 0; r < 4; r++) dst[r * 64] = f2bf(v[r]);
            } else {
                u16x4 pk;
                pk[0] = f2bf(v[0]); pk[1] = f2bf(v[1]);
                pk[2] = f2bf(v[2]); pk[3] = f2bf(v[3]);
                *(u16x4*)(vb + (bh * 64 + hd) * 1024 + nn) = pk;  // 4 consecutive n: 8B store
            }
        }
    }
}

// ---------------------------------------------------------------------------
// Kernel 2: flash attention. grid (16 q-tiles, 96 bh), block 256 = 4 waves,
// each wave owns 16 q-rows; KB=64 per iteration. Online softmax per q-row.
// K/V fragments read directly from global (L2/L3-resident, no LDS staging).
// P transposed through per-wave swizzled LDS for the PV A-operand.
// ---------------------------------------------------------------------------
__global__ __launch_bounds__(256) void attn_kernel(
    const ushort* __restrict__ qb, const ushort* __restrict__ kb,
    const ushort* __restrict__ vb, ushort* __restrict__ ao)
{
    __shared__ __align__(16) ushort Pl[4 * 16 * 64];   // 2KB per wave
    const int qt = blockIdx.x, bh = blockIdx.y;
    const int b = bh / 12, h = bh - b * 12;
    const int t = threadIdx.x, l = t & 63, w = t >> 6;
    const int lr = l & 15, lg = l >> 4;
    const int qr0 = qt * 64 + w * 16;
    char* Pb = (char*)(Pl + w * 16 * 64);

    // Q fragments (held for the whole kernel); SCALE already folded in.
    const ushort* qp = qb + (bh * 1024 + qr0 + lr) * 64 + lg * 8;
    const s16x8 qf0 = *(const s16x8*)qp;
    const s16x8 qf1 = *(const s16x8*)(qp + 32);

    float m_r[4] = {-__builtin_inff(), -__builtin_inff(), -__builtin_inff(), -__builtin_inff()};
    float l_r[4] = {0.f, 0.f, 0.f, 0.f};
    f32x4 o[4];
#pragma unroll
    for (int dc = 0; dc < 4; dc++) o[dc] = (f32x4){0.f, 0.f, 0.f, 0.f};

    const ushort* kbase = kb + bh * 65536 + lr * 64 + lg * 8;
    const ushort* vbase = vb + bh * 65536 + lr * 1024 + lg * 8;

    for (int kv0 = 0; kv0 < 1024; kv0 += 64) {
        // ---- S = Q K^T  (16 q-rows x 64 kv) ----
        f32x4 s[4];
#pragma unroll
        for (int c = 0; c < 4; c++) {
            const ushort* kp = kbase + (kv0 + c * 16) * 64;
            const s16x8 k0v = *(const s16x8*)kp;
            const s16x8 k1v = *(const s16x8*)(kp + 32);
            f32x4 tacc = (f32x4){0.f, 0.f, 0.f, 0.f};
            tacc = MFMA16(qf0, k0v, tacc);
            tacc = MFMA16(qf1, k1v, tacc);
            s[c] = tacc;
        }
        // ---- online softmax: row = lg*4+r, cols spread over c (in-lane) and lr ----
        float mx[4];
#pragma unroll
        for (int r = 0; r < 4; r++) {
            float v = fmaxf(fmaxf(s[0][r], s[1][r]), fmaxf(s[2][r], s[3][r]));
            v = fmaxf(v, __shfl_xor(v, 1));
            v = fmaxf(v, __shfl_xor(v, 2));
            v = fmaxf(v, __shfl_xor(v, 4));
            v = fmaxf(v, __shfl_xor(v, 8));
            mx[r] = v;
        }
        float fac[4], ps[4];
#pragma unroll
        for (int r = 0; r < 4; r++) {
            const float mn = fmaxf(m_r[r], mx[r]);
            fac[r] = __expf(m_r[r] - mn);     // first iter: exp(-inf)=0
            m_r[r] = mn;
            ps[r] = 0.f;
        }
#pragma unroll
        for (int c = 0; c < 4; c++) {
#pragma unroll
            for (int r = 0; r < 4; r++) {
                const float pv = __expf(s[c][r] - m_r[r]);
                ps[r] += pv;
                const int row = lg * 4 + r, col = c * 16 + lr;
                const int byte = (row * 128 + col * 2) ^ ((row & 7) << 4); // XOR swizzle
                *(ushort*)(Pb + byte) = f2bf(pv);
            }
        }
#pragma unroll
        for (int r = 0; r < 4; r++) {
            float v = ps[r];
            v += __shfl_xor(v, 1);
            v += __shfl_xor(v, 2);
            v += __shfl_xor(v, 4);
            v += __shfl_xor(v, 8);
            l_r[r] = l_r[r] * fac[r] + v;
        }
#pragma unroll
        for (int dc = 0; dc < 4; dc++) {
            o[dc][0] *= fac[0]; o[dc][1] *= fac[1];
            o[dc][2] *= fac[2]; o[dc][3] *= fac[3];
        }
        // ---- PV: A = P (row=q=lr, k=kv), wave-local LDS (in-order DS, no barrier) ----
        const s16x8 pa0 = *(const s16x8*)(Pb + ((lr * 128 +      lg * 16) ^ ((lr & 7) << 4)));
        const s16x8 pa1 = *(const s16x8*)(Pb + ((lr * 128 + 64 + lg * 16) ^ ((lr & 7) << 4)));
#pragma unroll
        for (int dc = 0; dc < 4; dc++) {
            const ushort* vp = vbase + dc * 16 * 1024 + kv0;
            const s16x8 v0 = *(const s16x8*)vp;
            const s16x8 v1 = *(const s16x8*)(vp + 32);
            o[dc] = MFMA16(pa0, v0, o[dc]);
            o[dc] = MFMA16(pa1, v1, o[dc]);
        }
    }
    // ---- epilogue: out[b][n][h*64+d] = o / l  (bf16 into ao) ----
    ushort* op = ao + (b * 1024 + qr0 + lg * 4) * 768 + h * 64 + lr;
#pragma unroll
    for (int r = 0; r < 4; r++) {
        const float inv = 1.f / l_r[r];
#pragma unroll
        for (int dc = 0; dc < 4; dc++)
            op[r * 768 + dc * 16] = f2bf(o[dc][r] * inv);
    }
}

// ---------------------------------------------------------------------------
// Kernel 3: out = attn_out @ proj_w^T + proj_b (fp32 out). grid (64, 6).
// ---------------------------------------------------------------------------
__global__ __launch_bounds__(256) void proj_gemm(
    const ushort* __restrict__ A, const ushort* __restrict__ W,
    const float* __restrict__ bias, float* __restrict__ out)
{
    __shared__ __align__(16) ushort As[128 * 32];
    __shared__ __align__(16) ushort Bs[128 * 32];
    f32x4 acc[4][4];
    const int br = blockIdx.x, bc = blockIdx.y;
    gemm128_mainloop(A, W, 768, br * 128, bc * 128, As, Bs, acc);

    const int t = threadIdx.x, l = t & 63, w = t >> 6;
    const int lr = l & 15, lg = l >> 4, wm = w >> 1, wn = w & 1;
    const int mrow0 = br * 128 + wm * 64 + lg * 4;
    const int ecolB = bc * 128 + wn * 64 + lr;

#pragma unroll
    for (int n = 0; n < 4; n++) {
        const int e = ecolB + n * 16;
        const float bv = bias[e];
#pragma unroll
        for (int m = 0; m < 4; m++) {
            const int mr = mrow0 + m * 16;
#pragma unroll
            for (int r = 0; r < 4; r++)
                out[(mr + r) * 768 + e] = acc[m][n][r] + bv;
        }
    }
}

// ---------------------------------------------------------------------------
extern "C" void kernel_launch(void* const* d_in, const int* in_sizes, int n_in,
                              void* d_out, int out_size, void* d_ws, size_t ws_size,
                              hipStream_t stream)
{
    const float* x  = (const float*)d_in[0];   // [8,1024,768] f32
    const float* wq = (const float*)d_in[1];   // [2304,768]   f32
    const float* wp = (const float*)d_in[2];   // [768,768]    f32
    const float* pb = (const float*)d_in[3];   // [768]        f32
    float* out = (float*)d_out;                // [8,1024,768] f32

    const int NX = 8 * 1024 * 768;             // 6291456
    const int NQ = 2304 * 768;                 // 1769472
    const int NP = 768 * 768;                  // 589824
    const int SEG = 8 * 12 * 1024 * 64;        // 6291456

    ushort* xb  = (ushort*)d_ws;               // x bf16; reused as ao after qkv
    ushort* wqb = xb + NX;
    ushort* wpb = wqb + NQ;
    ushort* qb  = wpb + NP;                    // q  [bh][n][64]  (pre-scaled)
    ushort* kb  = qb + SEG;                    // k  [bh][n][64]
    ushort* vb  = kb + SEG;                    // vT [bh][64][n]
    ushort* ao  = xb;                          // attn out aliases xb (dead by then)

    cvt_f32_bf16<<<2048, 256, 0, stream>>>(x,  xb,  NX / 4);
    cvt_f32_bf16<<<1024, 256, 0, stream>>>(wq, wqb, NQ / 4);
    cvt_f32_bf16<<<576,  256, 0, stream>>>(wp, wpb, NP / 4);

    qkv_gemm  <<<dim3(64, 18), 256, 0, stream>>>(xb, wqb, qb, kb, vb);
    attn_kernel<<<dim3(16, 96), 256, 0, stream>>>(qb, kb, vb, ao);
    proj_gemm <<<dim3(64, 6),  256, 0, stream>>>(ao, wpb, pb, out);
}

// Round 4
// 181.549 us; speedup vs baseline: 1.5987x; 1.5987x over previous
//
#include <hip/hip_runtime.h>

typedef unsigned short ushort;
typedef __attribute__((ext_vector_type(4)))  float  f32x4;
typedef __attribute__((ext_vector_type(16))) float  f32x16;
typedef __attribute__((ext_vector_type(8)))  short  s16x8;
typedef __attribute__((ext_vector_type(4)))  ushort u16x4;
typedef __attribute__((ext_vector_type(4)))  unsigned u32x4;

#define MFMA16(a, b, c) __builtin_amdgcn_mfma_f32_16x16x32_bf16((a), (b), (c), 0, 0, 0)
#define MFMA32(a, b, c) __builtin_amdgcn_mfma_f32_32x32x16_bf16((a), (b), (c), 0, 0, 0)

__device__ __forceinline__ ushort f2bf(float f) {
    unsigned u = __builtin_bit_cast(unsigned, f);
    u = (u + 0x7FFF + ((u >> 16) & 1)) >> 16;   // RNE
    return (ushort)u;
}

__device__ __forceinline__ unsigned cvtpk_bf16(float lo, float hi) {
    unsigned r;
    asm("v_cvt_pk_bf16_f32 %0, %1, %2" : "=v"(r) : "v"(lo), "v"(hi));
    return r;
}
// After the swap: a = [a_lo31 | b_lo31], b = [a_hi31 | b_hi31].
// NOTE: only safe when a and b are DISTINCT SSA values (else regalloc may
// coalesce both tied operands into one physreg -> self-swap corruption).
__device__ __forceinline__ void plswap(unsigned& a, unsigned& b) {
    asm volatile("v_permlane32_swap_b32 %0, %1" : "+v"(a), "+v"(b));
}
// Pair (lane ^ 32) reductions via verified __shfl_xor primitive.
__device__ __forceinline__ float pairmax(float x) {
    return fmaxf(x, __shfl_xor(x, 32));
}
__device__ __forceinline__ float pairsum(float x) {
    return x + __shfl_xor(x, 32);
}

__device__ __forceinline__ void gload_lds16(const ushort* g, ushort* l) {
    __builtin_amdgcn_global_load_lds(
        (const __attribute__((address_space(1))) void*)g,
        (__attribute__((address_space(3))) void*)l, 16, 0, 0);
}

// ---------------------------------------------------------------------------
// fp32 -> bf16 conversion (grid-stride, float4 in / 8B out)
// ---------------------------------------------------------------------------
__global__ __launch_bounds__(256) void cvt_f32_bf16(
    const float* __restrict__ in, ushort* __restrict__ out, int n4)
{
    int i = blockIdx.x * blockDim.x + threadIdx.x;
    const int stride = gridDim.x * blockDim.x;
    for (; i < n4; i += stride) {
        const float4 v = ((const float4*)in)[i];
        u16x4 o;
        o[0] = f2bf(v.x); o[1] = f2bf(v.y); o[2] = f2bf(v.z); o[3] = f2bf(v.w);
        ((u16x4*)out)[i] = o;
    }
}

// ---------------------------------------------------------------------------
// 128x128 tile GEMM mainloop (m97 structure), unchanged.
// ---------------------------------------------------------------------------
__device__ __forceinline__ void gemm128_mainloop(
    const ushort* __restrict__ A, const ushort* __restrict__ B, int K,
    int row0, int col0, ushort* As, ushort* Bs, f32x4 acc[4][4])
{
    const int t  = threadIdx.x;
    const int l  = t & 63;
    const int w  = t >> 6;
    const int lr = l & 15, lg = l >> 4;
    const int wm = w >> 1, wn = w & 1;

#pragma unroll
    for (int m = 0; m < 4; m++)
#pragma unroll
        for (int n = 0; n < 4; n++) acc[m][n] = (f32x4){0.f, 0.f, 0.f, 0.f};

    const ushort* ga0 = A + (row0 + (t >> 2)) * K + (t & 3) * 8;
    const ushort* gb0 = B + (col0 + (t >> 2)) * K + (t & 3) * 8;
    ushort* la0 = As + t * 8;
    ushort* lb0 = Bs + t * 8;
    const int rowsz = 64 * K;

    for (int k0 = 0; k0 < K; k0 += 32) {
        gload_lds16(ga0 + k0,          la0);
        gload_lds16(ga0 + rowsz + k0,  la0 + 2048);
        gload_lds16(gb0 + k0,          lb0);
        gload_lds16(gb0 + rowsz + k0,  lb0 + 2048);
        __syncthreads();

        s16x8 af[4], bfr[4];
#pragma unroll
        for (int m = 0; m < 4; m++)
            af[m] = *(const s16x8*)&As[(wm * 64 + m * 16 + lr) * 32 + lg * 8];
#pragma unroll
        for (int n = 0; n < 4; n++)
            bfr[n] = *(const s16x8*)&Bs[(wn * 64 + n * 16 + lr) * 32 + lg * 8];
#pragma unroll
        for (int m = 0; m < 4; m++)
#pragma unroll
            for (int n = 0; n < 4; n++)
                acc[m][n] = MFMA16(af[m], bfr[n], acc[m][n]);
        __syncthreads();
    }
}

// ---------------------------------------------------------------------------
// Kernel 1: QKV = x @ qkv_w^T, scatter into q[bh][n][64] (pre-scaled),
// k[bh][n][64], vT[bh][64][n].  grid (64, 18), block 256.
// ---------------------------------------------------------------------------
__global__ __launch_bounds__(256) void qkv_gemm(
    const ushort* __restrict__ X, const ushort* __restrict__ W,
    ushort* __restrict__ qb, ushort* __restrict__ kb, ushort* __restrict__ vb)
{
    __shared__ __align__(16) ushort As[128 * 32];
    __shared__ __align__(16) ushort Bs[128 * 32];
    f32x4 acc[4][4];
    const int br = blockIdx.x, bc = blockIdx.y;
    gemm128_mainloop(X, W, 768, br * 128, bc * 128, As, Bs, acc);

    const int t = threadIdx.x, l = t & 63, w = t >> 6;
    const int lr = l & 15, lg = l >> 4, wm = w >> 1, wn = w & 1;
    const int p = (bc * 128) / 768;
    const int mrow0 = br * 128 + wm * 64 + lg * 4;
    const int ecolB = bc * 128 + wn * 64 + lr;

#pragma unroll
    for (int n = 0; n < 4; n++) {
        const int e   = ecolB + n * 16;
        const int rem = e - p * 768;
        const int h   = rem >> 6;
        const int hd  = rem & 63;
#pragma unroll
        for (int m = 0; m < 4; m++) {
            const int mr = mrow0 + m * 16;
            const int b  = mr >> 10;
            const int nn = mr & 1023;
            const f32x4 v = acc[m][n];
            const int bh = b * 12 + h;
            if (p == 0) {
                ushort* dst = qb + (bh * 1024 + nn) * 64 + hd;
#pragma unroll
                for (int r = 0; r < 4; r++) dst[r * 64] = f2bf(v[r] * 0.125f);
            } else if (p == 1) {
                ushort* dst = kb + (bh * 1024 + nn) * 64 + hd;
#pragma unroll
                for (int r = 0; r < 4; r++) dst[r * 64] = f2bf(v[r]);
            } else {
                u16x4 pk;
                pk[0] = f2bf(v[0]); pk[1] = f2bf(v[1]);
                pk[2] = f2bf(v[2]); pk[3] = f2bf(v[3]);
                *(u16x4*)(vb + (bh * 64 + hd) * 1024 + nn) = pk;
            }
        }
    }
}

// ---------------------------------------------------------------------------
// Kernel 2: flash attention, 32x32 swapped-QK structure, zero LDS.
// grid (8 q-tiles of 128, 96 bh), block 256 = 4 waves; each wave owns 32 q.
// S^T = mfma(K, Q): lane holds S[k=crow(r,hi)][q=lq]; softmax in-register;
// P^T fragments via cvt_pk + permlane32_swap; O^T = mfma(V^T, P^T) so the
// per-q rescale is a lane-local scalar.
// ---------------------------------------------------------------------------
__global__ __launch_bounds__(256) void attn_kernel(
    const ushort* __restrict__ qb, const ushort* __restrict__ kb,
    const ushort* __restrict__ vb, ushort* __restrict__ ao)
{
    const int qt = blockIdx.x, bh = blockIdx.y;
    const int b = bh / 12, h = bh - b * 12;
    const int t = threadIdx.x, l = t & 63, w = t >> 6;
    const int lq = l & 31, hi = l >> 5;
    const int qr0 = qt * 128 + w * 32;

    // Q fragments: B-operand, col=q=lq, k=d-slice s*16 + hi*8
    const ushort* qlane = qb + (bh * 1024 + qr0 + lq) * 64 + hi * 8;
    s16x8 qf[4];
#pragma unroll
    for (int s = 0; s < 4; s++) qf[s] = *(const s16x8*)(qlane + s * 16);

    const ushort* klane = kb + bh * 65536 + lq * 64 + hi * 8;       // row=kv=lq
    const ushort* vlane = vb + (bh * 64 + lq) * 1024 + hi * 8;      // row=d=lq

    float m = -__builtin_inff();
    float lsum = 0.f;
    f32x16 o0 = {}, o1 = {};

    for (int kv0 = 0; kv0 < 1024; kv0 += 32) {
        // ---- K fragments (A-operand): row=kv0+lq, k=d-slice ----
        const ushort* kp = klane + kv0 * 64;
        const s16x8 kf0 = *(const s16x8*)kp;
        const s16x8 kf1 = *(const s16x8*)(kp + 16);
        const s16x8 kf2 = *(const s16x8*)(kp + 32);
        const s16x8 kf3 = *(const s16x8*)(kp + 48);

        f32x16 sa = {};
        __builtin_amdgcn_s_setprio(1);
        sa = MFMA32(kf0, qf[0], sa);
        sa = MFMA32(kf1, qf[1], sa);
        sa = MFMA32(kf2, qf[2], sa);
        sa = MFMA32(kf3, qf[3], sa);
        __builtin_amdgcn_s_setprio(0);

        // ---- in-register online softmax (16 k-values/lane, pair has rest) ----
        float mx = sa[0];
#pragma unroll
        for (int r = 1; r < 16; r++) mx = fmaxf(mx, sa[r]);
        mx = pairmax(mx);                     // max across lane^32 pair

        if (!__all(mx <= m + 8.f)) {          // defer-max (T13, THR=8)
            const float mn = fmaxf(m, mx);
            const float fac = __expf(m - mn); // first iter: exp(-inf)=0
            m = mn;
            lsum *= fac;
#pragma unroll
            for (int r = 0; r < 16; r++) { o0[r] *= fac; o1[r] *= fac; }
        }

        float p[16];
        float ps = 0.f;
#pragma unroll
        for (int r = 0; r < 16; r++) {
            p[r] = __expf(sa[r] - m);         // bounded by e^8
            ps += p[r];
        }
        lsum += pairsum(ps);                  // sum across lane^32 pair

        // ---- pack P^T into PV B-fragments (T12: cvt_pk + permlane32_swap) ----
        s16x8 pf[2];
#pragma unroll
        for (int slot = 0; slot < 2; slot++) {
            const int r0 = slot * 8;
            unsigned a0 = cvtpk_bf16(p[r0 + 0], p[r0 + 1]);
            unsigned a1 = cvtpk_bf16(p[r0 + 4], p[r0 + 5]);
            plswap(a0, a1);
            unsigned b0 = cvtpk_bf16(p[r0 + 2], p[r0 + 3]);
            unsigned b1 = cvtpk_bf16(p[r0 + 6], p[r0 + 7]);
            plswap(b0, b1);
            const u32x4 u = {a0, b0, a1, b1};
            pf[slot] = __builtin_bit_cast(s16x8, u);
        }

        // ---- PV: O^T += V^T * P^T ----
        const ushort* vp = vlane + kv0;
        const s16x8 v00 = *(const s16x8*)vp;
        const s16x8 v01 = *(const s16x8*)(vp + 16);
        const s16x8 v10 = *(const s16x8*)(vp + 32 * 1024);
        const s16x8 v11 = *(const s16x8*)(vp + 32 * 1024 + 16);
        __builtin_amdgcn_s_setprio(1);
        o0 = MFMA32(v00, pf[0], o0);
        o0 = MFMA32(v01, pf[1], o0);
        o1 = MFMA32(v10, pf[0], o1);
        o1 = MFMA32(v11, pf[1], o1);
        __builtin_amdgcn_s_setprio(0);
    }

    // ---- epilogue: out[b][q][h*64+d] = O^T[d][q] / lsum ----
    const float inv = 1.f / lsum;
    ushort* op = ao + (b * 1024 + qr0 + lq) * 768 + h * 64 + 4 * hi;
#pragma unroll
    for (int i = 0; i < 4; i++) {
        u16x4 pk0, pk1;
#pragma unroll
        for (int j = 0; j < 4; j++) {
            pk0[j] = f2bf(o0[4 * i + j] * inv);
            pk1[j] = f2bf(o1[4 * i + j] * inv);
        }
        *(u16x4*)(op + 8 * i)      = pk0;   // d = 8i+4hi + 0..3
        *(u16x4*)(op + 32 + 8 * i) = pk1;   // d = 32 + 8i+4hi + 0..3
    }
}

// ---------------------------------------------------------------------------
// Kernel 3: out = attn_out @ proj_w^T + proj_b (fp32 out). grid (64, 6).
// ---------------------------------------------------------------------------
__global__ __launch_bounds__(256) void proj_gemm(
    const ushort* __restrict__ A, const ushort* __restrict__ W,
    const float* __restrict__ bias, float* __restrict__ out)
{
    __shared__ __align__(16) ushort As[128 * 32];
    __shared__ __align__(16) ushort Bs[128 * 32];
    f32x4 acc[4][4];
    const int br = blockIdx.x, bc = blockIdx.y;
    gemm128_mainloop(A, W, 768, br * 128, bc * 128, As, Bs, acc);

    const int t = threadIdx.x, l = t & 63, w = t >> 6;
    const int lr = l & 15, lg = l >> 4, wm = w >> 1, wn = w & 1;
    const int mrow0 = br * 128 + wm * 64 + lg * 4;
    const int ecolB = bc * 128 + wn * 64 + lr;

#pragma unroll
    for (int n = 0; n < 4; n++) {
        const int e = ecolB + n * 16;
        const float bv = bias[e];
#pragma unroll
        for (int m = 0; m < 4; m++) {
            const int mr = mrow0 + m * 16;
#pragma unroll
            for (int r = 0; r < 4; r++)
                out[(mr + r) * 768 + e] = acc[m][n][r] + bv;
        }
    }
}

// ---------------------------------------------------------------------------
extern "C" void kernel_launch(void* const* d_in, const int* in_sizes, int n_in,
                              void* d_out, int out_size, void* d_ws, size_t ws_size,
                              hipStream_t stream)
{
    const float* x  = (const float*)d_in[0];   // [8,1024,768] f32
    const float* wq = (const float*)d_in[1];   // [2304,768]   f32
    const float* wp = (const float*)d_in[2];   // [768,768]    f32
    const float* pb = (const float*)d_in[3];   // [768]        f32
    float* out = (float*)d_out;                // [8,1024,768] f32

    const int NX = 8 * 1024 * 768;             // 6291456
    const int NQ = 2304 * 768;                 // 1769472
    const int NP = 768 * 768;                  // 589824
    const int SEG = 8 * 12 * 1024 * 64;        // 6291456

    ushort* xb  = (ushort*)d_ws;               // x bf16; reused as ao after qkv
    ushort* wqb = xb + NX;
    ushort* wpb = wqb + NQ;
    ushort* qb  = wpb + NP;                    // q  [bh][n][64]  (pre-scaled)
    ushort* kb  = qb + SEG;                    // k  [bh][n][64]
    ushort* vb  = kb + SEG;                    // vT [bh][64][n]
    ushort* ao  = xb;                          // attn out aliases xb (dead by then)

    cvt_f32_bf16<<<2048, 256, 0, stream>>>(x,  xb,  NX / 4);
    cvt_f32_bf16<<<1024, 256, 0, stream>>>(wq, wqb, NQ / 4);
    cvt_f32_bf16<<<576,  256, 0, stream>>>(wp, wpb, NP / 4);

    qkv_gemm  <<<dim3(64, 18), 256, 0, stream>>>(xb, wqb, qb, kb, vb);
    attn_kernel<<<dim3(8, 96), 256, 0, stream>>>(qb, kb, vb, ao);
    proj_gemm <<<dim3(64, 6),  256, 0, stream>>>(ao, wpb, pb, out);
}